// Round 6
// baseline (65.182 us; speedup 1.0000x reference)
//
#include <hip/hip_runtime.h>
#include <hip/hip_bf16.h>

typedef unsigned int u32;
typedef unsigned short u16;
typedef unsigned long long u64;

#define BATCH 256
#define NN 4096
#define DIM 512
#define NBLK 256

using short8 = __attribute__((ext_vector_type(8))) short;
using f32x4  = __attribute__((ext_vector_type(4))) float;

__device__ inline float b2f(u16 u){ u32 i = ((u32)u)<<16; float f; __builtin_memcpy(&f,&i,4); return f; }
__device__ inline u16 f2b(float v){ __hip_bfloat16 h = __float2bfloat16(v); u16 r; __builtin_memcpy(&r,&h,2); return r; }

__device__ inline float ldv(const void* p, size_t i, int isbf){
  return isbf ? b2f(((const u16*)p)[i]) : ((const float*)p)[i];
}
__device__ inline void stv(void* p, size_t i, float v, int isbf){
  if (isbf) ((__hip_bfloat16*)p)[i] = __float2bfloat16(v);
  else ((float*)p)[i] = v;
}

__device__ inline int sniff(const void* X, int t, int* sh){
  if (t < 64){
    u32 v = ((const u32*)X)[t];
    u16 lo = (u16)(v & 0xffffu);
    int e = (lo >> 7) & 0xff;
    int sane = ((lo & 0x7fffu) == 0) || (e >= 110 && e <= 132);
    u64 m = __ballot(sane);
    if (t == 0) *sh = (__popcll(m) >= 32) ? 1 : 0;
  }
  __syncthreads();
  return *sh;
}

// Mono-kernel: 256 blocks x 512 threads, guaranteed co-resident (1 block/CU cap).
// Phase A: XT slice + coalesced w2 + MFMA score -> pack2 partials.
// Hand-rolled device barrier (release-add / relaxed-spin / one acquire).
// Phase B: pack2 reduce -> bmu -> h tile -> MFMA hX -> fused SOM update.
__global__ __launch_bounds__(512) void k_mono(const void* X, const void* W,
    u16* Xb, u16* Wb, u16* XT, u64* pack2, u32* counter,
    const int* passo, const int* total, void* out){
  __shared__ int sflag;
  __shared__ float sw2[128];
  __shared__ float sval[4][32];
  __shared__ int   sidx[4][32];
  __shared__ u64 smin[512];
  __shared__ int sbmu[256];
  __shared__ u16 hT[16][264];
  __shared__ float hpart[8][8];
  __shared__ float hs[16];

  int t = threadIdx.x;
  int isbf = sniff(X, t, &sflag);
  int blk = blockIdx.x;
  int wv = t>>6, l = t&63, lr = l&15, lg = l>>4;
  int xcd = blk & 7, sub = blk >> 3;
  int ny = xcd*4 + (sub>>3);           // n-chunk 0..31 (4 per XCD)
  int bx = sub & 7;                    // b-tile 0..7
  int b0 = bx*32;
  int nbase = ny*128;

  // ---- Phase A0: XT slice (d = blk*2 + t>>8, b = t&255) ----
  {
    int d = blk*2 + (t>>8);
    int b = t & 255;
    XT[(size_t)d*BATCH + b] = f2b(ldv(X, (size_t)b*DIM + d, isbf));
  }
  if (!isbf){
    for (int i=t; i<32*DIM; i+=512){   // this block's X rows (benign overlap)
      size_t gi = (size_t)(b0 + (i>>9))*DIM + (i&511);
      Xb[gi] = f2b(((const float*)X)[gi]);
    }
  }
  // ---- Phase A1: w2, coalesced (quarter-wave per row; 4 rows/wave/iter) ----
  #pragma unroll
  for (int it=0; it<4; ++it){
    int r = wv*16 + it*4 + (l>>4);     // 0..127
    size_t base = (size_t)(nbase + r)*DIM + (l&15)*32;
    float s = 0.f;
    if (isbf){
      const u16* wp = (const u16*)W + base;
      #pragma unroll
      for (int j=0;j<4;++j){
        short8 x = *(const short8*)(wp + j*8);
        #pragma unroll
        for (int q=0;q<8;++q){ float f = b2f((u16)x[q]); s += f*f; }
      }
    } else {
      const float* wp = (const float*)W + base;
      #pragma unroll
      for (int i=0;i<32;++i){ float f = wp[i]; s += f*f; Wb[base+i] = f2b(f); }
    }
    s += __shfl_xor(s, 1);
    s += __shfl_xor(s, 2);
    s += __shfl_xor(s, 4);
    s += __shfl_xor(s, 8);
    if ((l&15) == 0) sw2[r] = s;
  }
  __syncthreads();

  // ---- Phase A2: MFMA score. 8 waves = 2 b-halves x 4 n-quarters ----
  {
    const u16* Xp = isbf ? (const u16*)X : Xb;
    const u16* Wp = isbf ? (const u16*)W : Wb;
    int bh = (wv&1)*16;
    int nq = (wv>>1)*32;
    int n0 = nbase + nq;
    const u16* xp  = Xp + (size_t)(b0 + bh + lr)*DIM + lg*8;
    const u16* wp0 = Wp + (size_t)(n0 + lr)*DIM + lg*8;
    const u16* wp1 = wp0 + (size_t)16*DIM;

    f32x4 acc0 = {0,0,0,0}, acc1 = {0,0,0,0};
    #pragma unroll
    for (int ks=0; ks<16; ++ks){
      short8 a  = *(const short8*)(xp  + ks*32);
      short8 w0 = *(const short8*)(wp0 + ks*32);
      short8 w1 = *(const short8*)(wp1 + ks*32);
      acc0 = __builtin_amdgcn_mfma_f32_16x16x32_bf16(a, w0, acc0, 0,0,0);
      acc1 = __builtin_amdgcn_mfma_f32_16x16x32_bf16(a, w1, acc1, 0,0,0);
    }

    float w20 = sw2[nq + lr];
    float w21 = sw2[nq + 16 + lr];
    #pragma unroll
    for (int r=0;r<4;++r){
      float s0 = w20 - 2.f*acc0[r];
      float s1 = w21 - 2.f*acc1[r];
      float bv; int bi;
      if (s0 <= s1){ bv = s0; bi = n0 + lr; } else { bv = s1; bi = n0 + 16 + lr; }
      #pragma unroll
      for (int m=1; m<16; m<<=1){
        float ov = __shfl_xor(bv, m);
        int   oi = __shfl_xor(bi, m);
        if (ov < bv || (ov == bv && oi < bi)){ bv = ov; bi = oi; }
      }
      if (lr == 0){
        sval[wv>>1][bh + lg*4 + r] = bv;
        sidx[wv>>1][bh + lg*4 + r] = bi;
      }
    }
    __syncthreads();
    if (t < 32){                       // one write per (ny,b) slot, no atomics
      float bv = sval[0][t]; int bi = sidx[0][t];
      #pragma unroll
      for (int qc=1; qc<4; ++qc){
        float ov = sval[qc][t]; int oi = sidx[qc][t];
        if (ov < bv || (ov == bv && oi < bi)){ bv = ov; bi = oi; }
      }
      u32 sb = __float_as_uint(bv);
      sb = (sb & 0x80000000u) ? ~sb : (sb | 0x80000000u);
      pack2[(size_t)ny*BATCH + b0 + t] = ((u64)sb << 32) | (u32)bi;
    }
  }

  // ---- Grid barrier: release-add, read-through spin, one acquire ----
  __syncthreads();                      // all 512 threads' stores drained (vmcnt 0)
  if (t == 0){
    __hip_atomic_fetch_add(counter, 1u, __ATOMIC_RELEASE, __HIP_MEMORY_SCOPE_AGENT);
    while (__hip_atomic_load(counter, __ATOMIC_RELAXED, __HIP_MEMORY_SCOPE_AGENT) < NBLK)
      __builtin_amdgcn_s_sleep(2);
    (void)__hip_atomic_load(counter, __ATOMIC_ACQUIRE, __HIP_MEMORY_SCOPE_AGENT);
  }
  __syncthreads();

  // ---- Phase B0: final argmin across 32 chunks ----
  {
    int b = t & 255, half = t >> 8;
    u64 m = ~0ull;
    #pragma unroll
    for (int c=0;c<16;++c){
      u64 v = pack2[(size_t)(half*16 + c)*BATCH + b];
      if (v < m) m = v;
    }
    smin[t] = m;
  }
  __syncthreads();
  if (t < 256){
    u64 m = smin[t] < smin[t+256] ? smin[t] : smin[t+256];
    sbmu[t] = (int)(u32)(m & 0xffffffffu);
  }
  __syncthreads();

  float decay = expf(-(float)passo[0] / (float)total[0]);
  float taxa = 0.5f*decay, sigma = 32.f*decay;
  float inv2s2 = 1.f/(2.f*sigma*sigma);
  if (blk == 0 && t == 0){
    stv(out, (size_t)NN*DIM,     taxa,  isbf);
    stv(out, (size_t)NN*DIM + 1, sigma, isbf);
  }

  // ---- Phase B1: h tile + row sums (block owns rows n0..n0+15) ----
  int n0u = blk * 16;
  {
    int b = t & 255;
    int rbase = (t >> 8) * 8;
    int m = sbmu[b];
    int mx = m & 63, my = m >> 6;
    float hv[8];
    #pragma unroll
    for (int i=0;i<8;++i){
      int n = n0u + rbase + i;
      int dx = (n & 63) - mx;
      int dy = (n >> 6) - my;
      float h = expf(-(float)(dx*dx + dy*dy) * inv2s2);
      hv[i] = h;
      hT[rbase + i][b] = f2b(h);
    }
    #pragma unroll
    for (int i=0;i<8;++i){
      float s = hv[i];
      #pragma unroll
      for (int off=32; off; off>>=1) s += __shfl_down(s, off);
      if (l == 0) hpart[wv][i] = s;
    }
  }
  __syncthreads();
  if (t < 16){
    int g = (t >> 3) * 4;
    hs[t] = hpart[g][t&7] + hpart[g+1][t&7] + hpart[g+2][t&7] + hpart[g+3][t&7];
  }
  __syncthreads();

  // ---- Phase B2: MFMA hX + fused update ----
  {
    int d0 = wv * 64;
    f32x4 acc[4];
    #pragma unroll
    for (int f=0;f<4;++f) acc[f] = (f32x4){0.f,0.f,0.f,0.f};

    #pragma unroll
    for (int ks=0; ks<8; ++ks){
      short8 a = *(const short8*)(&hT[lr][ks*32 + lg*8]);
      #pragma unroll
      for (int f=0; f<4; ++f){
        short8 bfr = *(const short8*)(XT + (size_t)(d0 + f*16 + lr)*BATCH + ks*32 + lg*8);
        acc[f] = __builtin_amdgcn_mfma_f32_16x16x32_bf16(a, bfr, acc[f], 0,0,0);
      }
    }

    float cc = taxa / (float)BATCH;
    #pragma unroll
    for (int r=0;r<4;++r){
      int n = n0u + lg*4 + r;
      float hsv = hs[lg*4 + r];
      #pragma unroll
      for (int f=0;f<4;++f){
        size_t gi = (size_t)n*DIM + d0 + f*16 + lr;
        float wv_ = ldv(W, gi, isbf);
        float o = wv_ + cc*(acc[f][r] - hsv*wv_);
        stv(out, gi, o, isbf);
      }
    }
  }
}

extern "C" void kernel_launch(void* const* d_in, const int* in_sizes, int n_in,
                              void* d_out, int out_size, void* d_ws, size_t ws_size,
                              hipStream_t stream) {
  const void* X = d_in[0];      // (256, 512)
  const void* W = d_in[1];      // (4096, 512)
  // d_in[2] = localizacoes — recomputed on device as (n%64, n/64)
  const int* passo = (const int*)d_in[3];
  const int* total = (const int*)d_in[4];

  char* ws = (char*)d_ws;
  u32* counter = (u32*)(ws + 0);        // 4 B, zeroed per call below
  u64* pack2   = (u64*)(ws + 256);      // 32*256*8 = 65536
  u16* XT      = (u16*)(ws + 256 + 65536);             // 512*256*2 = 262144
  u16* Xb      = (u16*)(ws + 256 + 65536 + 262144);    // f32 fallback
  u16* Wb      = (u16*)(ws + 256 + 65536 + 262144 + 262144); // f32 fallback (4 MiB)

  hipMemsetAsync(counter, 0, 4, stream);   // graph-capturable async memset
  k_mono<<<NBLK, 512, 0, stream>>>(X, W, Xb, Wb, XT, pack2, counter,
                                   passo, total, d_out);
}

// Round 7
// 62.817 us; speedup vs baseline: 1.0376x; 1.0376x over previous
//
#include <hip/hip_runtime.h>
#include <hip/hip_bf16.h>

typedef unsigned int u32;
typedef unsigned short u16;
typedef unsigned long long u64;

#define BATCH 256
#define NN 4096
#define DIM 512

using short8 = __attribute__((ext_vector_type(8))) short;
using f32x4  = __attribute__((ext_vector_type(4))) float;

__device__ inline float b2f(u16 u){ u32 i = ((u32)u)<<16; float f; __builtin_memcpy(&f,&i,4); return f; }
__device__ inline u16 f2b(float v){ __hip_bfloat16 h = __float2bfloat16(v); u16 r; __builtin_memcpy(&r,&h,2); return r; }

__device__ inline float ldv(const void* p, size_t i, int isbf){
  return isbf ? b2f(((const u16*)p)[i]) : ((const float*)p)[i];
}
__device__ inline void stv(void* p, size_t i, float v, int isbf){
  if (isbf) ((__hip_bfloat16*)p)[i] = __float2bfloat16(v);
  else ((float*)p)[i] = v;
}

__device__ inline int sniff(const void* X, int t, int* sh){
  if (t < 64){
    u32 v = ((const u32*)X)[t];
    u16 lo = (u16)(v & 0xffffu);
    int e = (lo >> 7) & 0xff;
    int sane = ((lo & 0x7fffu) == 0) || (e >= 110 && e <= 132);
    u64 m = __ballot(sane);
    if (t == 0) *sh = (__popcll(m) >= 32) ? 1 : 0;
  }
  __syncthreads();
  return *sh;
}

// kA: XT slice + MFMA score with w2 FOLDED into the K-loop (zero extra traffic)
//     -> race-free pack2 partial-argmin write. 512 blocks x 256 thr (2 blocks/CU).
// Block (bx,ny) = 16 b x 128 n; wave = 16b x 32n. XCD-grouped: the 16 blocks
// sharing an n-chunk's 128 W rows land on one XCD's L2.
__global__ __launch_bounds__(256, 2) void kA_score(const void* X, const void* W,
    u16* Xb, u16* Wb, u16* XT, u64* pack2){
  __shared__ int sflag;
  __shared__ float sval[4][16];
  __shared__ int   sidx[4][16];
  int t = threadIdx.x;
  int isbf = sniff(X, t, &sflag);
  int blk = blockIdx.x;                 // 512
  int wv = t>>6, l = t&63, lr = l&15, lg = l>>4;
  int xcd = blk & 7, sub = blk >> 3;    // 64 blocks per XCD
  int ny  = xcd*4 + (sub>>4);           // n-chunk 0..31 (4 per XCD)
  int bx  = sub & 15;                   // b-tile 0..15
  int b0 = bx*16;
  int nbase = ny*128;
  int n0 = nbase + wv*32;

  // XT slice: thread's element idx = blk*256 + t -> d = blk, b = t
  XT[(size_t)blk*BATCH + t] = f2b(ldv(X, (size_t)t*DIM + blk, isbf));

  if (!isbf){                           // f32 fallback: block-local converts only
    for (int i=t; i<16*DIM; i+=256){
      size_t gi = (size_t)(b0 + (i>>9))*DIM + (i&511);
      Xb[gi] = f2b(((const float*)X)[gi]);
    }
    for (int i=t; i<128*DIM; i+=256){   // own chunk (redundant across b-tiles, benign)
      size_t gi = (size_t)(nbase + (i>>9))*DIM + (i&511);
      Wb[gi] = f2b(((const float*)W)[gi]);
    }
    __syncthreads();
  }
  const u16* Xp = isbf ? (const u16*)X : Xb;
  const u16* Wp = isbf ? (const u16*)W : Wb;

  const u16* xp  = Xp + (size_t)(b0 + lr)*DIM + lg*8;
  const u16* wp0 = Wp + (size_t)(n0 + lr)*DIM + lg*8;
  const u16* wp1 = wp0 + (size_t)16*DIM;

  f32x4 acc0 = {0,0,0,0}, acc1 = {0,0,0,0};
  float sq0 = 0.f, sq1 = 0.f;           // w2 partials from the SAME fragments
  #pragma unroll
  for (int ks=0; ks<16; ++ks){
    short8 a  = *(const short8*)(xp  + ks*32);
    short8 w0 = *(const short8*)(wp0 + ks*32);
    short8 w1 = *(const short8*)(wp1 + ks*32);
    acc0 = __builtin_amdgcn_mfma_f32_16x16x32_bf16(a, w0, acc0, 0,0,0);
    acc1 = __builtin_amdgcn_mfma_f32_16x16x32_bf16(a, w1, acc1, 0,0,0);
    #pragma unroll
    for (int q=0;q<8;++q){
      float f0 = b2f((u16)w0[q]); sq0 = fmaf(f0, f0, sq0);
      float f1 = b2f((u16)w1[q]); sq1 = fmaf(f1, f1, sq1);
    }
  }
  // lane (lr,lg) holds squares over k ≡ lg*8 (mod 32); combine the 4 lg-groups
  sq0 += __shfl_xor(sq0, 16); sq0 += __shfl_xor(sq0, 32);
  sq1 += __shfl_xor(sq1, 16); sq1 += __shfl_xor(sq1, 32);

  #pragma unroll
  for (int r=0;r<4;++r){
    float s0 = sq0 - 2.f*acc0[r];
    float s1 = sq1 - 2.f*acc1[r];
    float bv; int bi;
    if (s0 <= s1){ bv = s0; bi = n0 + lr; } else { bv = s1; bi = n0 + 16 + lr; }
    #pragma unroll
    for (int m=1; m<16; m<<=1){
      float ov = __shfl_xor(bv, m);
      int   oi = __shfl_xor(bi, m);
      if (ov < bv || (ov == bv && oi < bi)){ bv = ov; bi = oi; }
    }
    if (lr == 0){ sval[wv][lg*4 + r] = bv; sidx[wv][lg*4 + r] = bi; }
  }
  __syncthreads();
  if (t < 16){                          // one write per (ny,b) slot, no atomics/init
    float bv = sval[0][t]; int bi = sidx[0][t];
    #pragma unroll
    for (int qc=1; qc<4; ++qc){
      float ov = sval[qc][t]; int oi = sidx[qc][t];
      if (ov < bv || (ov == bv && oi < bi)){ bv = ov; bi = oi; }
    }
    u32 sb = __float_as_uint(bv);
    sb = (sb & 0x80000000u) ? ~sb : (sb | 0x80000000u);
    pack2[(size_t)ny*BATCH + b0 + t] = ((u64)sb << 32) | (u32)bi;
  }
}

// kB: pack2 reduce -> bmu -> h tile -> MFMA hX -> fused SOM update.
// 256 blocks x 512 threads; block owns 16 n rows; wave wv covers d in [wv*64,+64).
__global__ __launch_bounds__(512) void kB_update(const void* X, const u16* XT, const void* W,
    const u64* pack2, const int* passo, const int* total, void* out){
  __shared__ int sflag;
  __shared__ u64 smin[512];
  __shared__ int sbmu[256];
  __shared__ u16 hT[16][264];
  __shared__ float hpart[8][8];
  __shared__ float hs[16];
  int t = threadIdx.x;
  int isbf = sniff(X, t, &sflag);
  int wv = t>>6, l = t&63, lr = l&15, lg = l>>4;
  int n0 = blockIdx.x * 16;

  // ---- final argmin across the 32 chunks (L2-broadcast reads) ----
  {
    int b = t & 255, half = t >> 8;
    u64 m = ~0ull;
    #pragma unroll
    for (int c=0;c<16;++c){
      u64 v = pack2[(size_t)(half*16 + c)*BATCH + b];
      if (v < m) m = v;
    }
    smin[t] = m;
  }
  __syncthreads();
  if (t < 256){
    u64 m = smin[t] < smin[t+256] ? smin[t] : smin[t+256];
    sbmu[t] = (int)(u32)(m & 0xffffffffu);
  }
  __syncthreads();

  float decay = expf(-(float)passo[0] / (float)total[0]);
  float taxa = 0.5f*decay, sigma = 32.f*decay;
  float inv2s2 = 1.f/(2.f*sigma*sigma);
  if (blockIdx.x == 0 && t == 0){
    stv(out, (size_t)NN*DIM,     taxa,  isbf);
    stv(out, (size_t)NN*DIM + 1, sigma, isbf);
  }

  // ---- h tile + row sums ----
  {
    int b = t & 255;
    int rbase = (t >> 8) * 8;
    int m = sbmu[b];
    int mx = m & 63, my = m >> 6;
    float hv[8];
    #pragma unroll
    for (int i=0;i<8;++i){
      int n = n0 + rbase + i;
      int dx = (n & 63) - mx;
      int dy = (n >> 6) - my;
      float h = expf(-(float)(dx*dx + dy*dy) * inv2s2);
      hv[i] = h;
      hT[rbase + i][b] = f2b(h);
    }
    #pragma unroll
    for (int i=0;i<8;++i){
      float s = hv[i];
      #pragma unroll
      for (int off=32; off; off>>=1) s += __shfl_down(s, off);
      if (l == 0) hpart[wv][i] = s;
    }
  }
  __syncthreads();
  if (t < 16){
    int g = (t >> 3) * 4;
    hs[t] = hpart[g][t&7] + hpart[g+1][t&7] + hpart[g+2][t&7] + hpart[g+3][t&7];
  }
  __syncthreads();

  // ---- MFMA hX + fused update ----
  int d0 = wv * 64;
  f32x4 acc[4];
  #pragma unroll
  for (int f=0;f<4;++f) acc[f] = (f32x4){0.f,0.f,0.f,0.f};

  #pragma unroll
  for (int ks=0; ks<8; ++ks){
    short8 a = *(const short8*)(&hT[lr][ks*32 + lg*8]);
    #pragma unroll
    for (int f=0; f<4; ++f){
      short8 bfr = *(const short8*)(XT + (size_t)(d0 + f*16 + lr)*BATCH + ks*32 + lg*8);
      acc[f] = __builtin_amdgcn_mfma_f32_16x16x32_bf16(a, bfr, acc[f], 0,0,0);
    }
  }

  float cc = taxa / (float)BATCH;
  #pragma unroll
  for (int r=0;r<4;++r){
    int n = n0 + lg*4 + r;
    float hsv = hs[lg*4 + r];
    #pragma unroll
    for (int f=0;f<4;++f){
      size_t gi = (size_t)n*DIM + d0 + f*16 + lr;
      float wv_ = ldv(W, gi, isbf);
      float o = wv_ + cc*(acc[f][r] - hsv*wv_);
      stv(out, gi, o, isbf);
    }
  }
}

extern "C" void kernel_launch(void* const* d_in, const int* in_sizes, int n_in,
                              void* d_out, int out_size, void* d_ws, size_t ws_size,
                              hipStream_t stream) {
  const void* X = d_in[0];      // (256, 512)
  const void* W = d_in[1];      // (4096, 512)
  // d_in[2] = localizacoes — recomputed on device as (n%64, n/64)
  const int* passo = (const int*)d_in[3];
  const int* total = (const int*)d_in[4];

  char* ws = (char*)d_ws;
  u64* pack2 = (u64*)(ws + 0);          // 32*256*8 = 65536
  u16* XT    = (u16*)(ws + 65536);      // 512*256*2 = 262144
  u16* Xb    = (u16*)(ws + 327680);     // f32 fallback
  u16* Wb    = (u16*)(ws + 589824);     // f32 fallback (4 MiB)

  kA_score <<<512, 256, 0, stream>>>(X, W, Xb, Wb, XT, pack2);
  kB_update<<<256, 512, 0, stream>>>(X, XT, W, pack2, passo, total, d_out);
}

// Round 8
// 41.490 us; speedup vs baseline: 1.5710x; 1.5140x over previous
//
#include <hip/hip_runtime.h>
#include <hip/hip_bf16.h>

typedef unsigned int u32;
typedef unsigned short u16;
typedef unsigned long long u64;

#define BATCH 256
#define NN 4096
#define DIM 512

using short8 = __attribute__((ext_vector_type(8))) short;
using f32x4  = __attribute__((ext_vector_type(4))) float;

__device__ inline float b2f(u16 u){ u32 i = ((u32)u)<<16; float f; __builtin_memcpy(&f,&i,4); return f; }
__device__ inline u16 f2b(float v){ __hip_bfloat16 h = __float2bfloat16(v); u16 r; __builtin_memcpy(&r,&h,2); return r; }

__device__ inline float ldv(const void* p, size_t i, int isbf){
  return isbf ? b2f(((const u16*)p)[i]) : ((const float*)p)[i];
}
__device__ inline void stv(void* p, size_t i, float v, int isbf){
  if (isbf) ((__hip_bfloat16*)p)[i] = __float2bfloat16(v);
  else ((float*)p)[i] = v;
}

__device__ inline int sniff(const void* X, int t, int* sh){
  if (t < 64){
    u32 v = ((const u32*)X)[t];
    u16 lo = (u16)(v & 0xffffu);
    int e = (lo >> 7) & 0xff;
    int sane = ((lo & 0x7fffu) == 0) || (e >= 110 && e <= 132);
    u64 m = __ballot(sane);
    if (t == 0) *sh = (__popcll(m) >= 32) ? 1 : 0;
  }
  __syncthreads();
  return *sh;
}

// K_prep: blocks 0..31  -> XT via coalesced 64x64 LDS tile transpose (+Xb convert)
//         blocks 32..543 -> w2 for 8 W rows each (+Wb convert); block 32: pack init + scalars.
// NO strided gathers anywhere (r7 post-mortem: stride-1KB wave64 gathers stall ~10-15us).
__global__ __launch_bounds__(256) void k_prep(const void* X, const void* W,
    u64* pack, float* w2, u16* XT, u16* Xb, u16* Wb,
    const int* passo, const int* total, void* out){
  __shared__ int sflag;
  __shared__ u32 sT[64][33];   // 64 b-rows x 32 d-pairs (+1 pad)
  int t = threadIdx.x;
  int isbf = sniff(X, t, &sflag);
  int blk = blockIdx.x;
  if (blk < 32){
    int td = blk & 7, tb = blk >> 3;   // d-tile 0..7 (64 d), b-tile 0..3 (64 b)
    // read phase: X[tb*64+r][td*64 + cc*2 .. +1] -> sT[r][cc], contiguous 128B/row
    #pragma unroll
    for (int it=0; it<8; ++it){
      int i = it*256 + t;
      int r = i>>5, cc = i&31;
      size_t gi = (size_t)(tb*64 + r)*DIM + td*64 + cc*2;
      u32 v;
      if (isbf){
        v = *(const u32*)((const u16*)X + gi);
      } else {
        float2 f = *(const float2*)((const float*)X + gi);
        v = (u32)f2b(f.x) | ((u32)f2b(f.y) << 16);
        *(u32*)(Xb + gi) = v;
      }
      sT[r][cc] = v;
    }
    __syncthreads();
    // write phase: XT[td*64+dd][tb*64 + bb2*2 .. +1], contiguous 128B/row
    #pragma unroll
    for (int it=0; it<8; ++it){
      int i = it*256 + t;
      int dd = i>>5, bb2 = i&31;
      u32 lo = sT[bb2*2][dd>>1], hi = sT[bb2*2+1][dd>>1];
      int sh = (dd&1)*16;
      u32 v = ((lo >> sh) & 0xffffu) | (((hi >> sh) & 0xffffu) << 16);
      *(u32*)(XT + (size_t)(td*64+dd)*BATCH + tb*64 + bb2*2) = v;
    }
  } else {
    int j = blk - 32;                  // 0..511, rows n0..n0+7
    int n0 = j*8;
    int wv = t>>6, lane = t&63;
    #pragma unroll
    for (int rr=0; rr<2; ++rr){
      int n = n0 + wv*2 + rr;
      float xv[8]; float s = 0.f;
      if (isbf){
        short8 x = *(const short8*)((const u16*)W + (size_t)n*DIM + lane*8);
        #pragma unroll
        for (int q=0;q<8;q++) xv[q] = b2f((u16)x[q]);
      } else {
        #pragma unroll
        for (int q=0;q<8;q++) xv[q] = ((const float*)W)[(size_t)n*DIM + lane*8 + q];
      }
      #pragma unroll
      for (int q=0;q<8;q++) s += xv[q]*xv[q];
      #pragma unroll
      for (int off=32; off; off>>=1) s += __shfl_down(s, off);
      if (lane == 0) w2[n] = s;
      if (!isbf){
        #pragma unroll
        for (int q=0;q<8;q++) Wb[(size_t)n*DIM + lane*8 + q] = f2b(xv[q]);
      }
    }
    if (j == 0){
      pack[t] = ~0ull;
      if (t == 0){
        float decay = expf(-(float)passo[0]/(float)total[0]);
        stv(out, (size_t)NN*DIM,     0.5f*decay, isbf);
        stv(out, (size_t)NN*DIM + 1, 32.f*decay, isbf);
      }
    }
  }
}

// K_score (r3 verbatim): MFMA score + fused argmin. Wave tile 32b x 32n (2x2).
// 256 blocks (1/CU): 8 b-tiles x 32 n-chunks, XCD-grouped.
__global__ __launch_bounds__(256) void k_score(const void* X, const void* W,
    const u16* Xws, const u16* Wws, const float* w2, u64* pack){
  __shared__ int sflag;
  __shared__ float sval[4][32];
  __shared__ int   sidx[4][32];
  int t = threadIdx.x;
  int isbf = sniff(X, t, &sflag);
  const u16* Xb = isbf ? (const u16*)X : Xws;
  const u16* Wb = isbf ? (const u16*)W : Wws;
  int wv = t>>6, l = t&63;
  int lr = l&15, lg = l>>4;

  int id = blockIdx.x;
  int xcd = id & 7, sub = id >> 3;
  int ny = xcd*4 + (sub>>3);
  int bx = sub & 7;
  int b0 = bx*32;
  int n0 = ny*128 + wv*32;

  const u16* xp0 = Xb + (size_t)(b0 + lr)*DIM + lg*8;
  const u16* xp1 = xp0 + (size_t)16*DIM;
  const u16* wp0 = Wb + (size_t)(n0 + lr)*DIM + lg*8;
  const u16* wp1 = wp0 + (size_t)16*DIM;

  f32x4 acc00 = {0,0,0,0}, acc01 = {0,0,0,0}, acc10 = {0,0,0,0}, acc11 = {0,0,0,0};
  #pragma unroll
  for (int ks=0; ks<16; ++ks){
    short8 a0 = *(const short8*)(xp0 + ks*32);
    short8 a1 = *(const short8*)(xp1 + ks*32);
    short8 w0 = *(const short8*)(wp0 + ks*32);
    short8 w1 = *(const short8*)(wp1 + ks*32);
    acc00 = __builtin_amdgcn_mfma_f32_16x16x32_bf16(a0, w0, acc00, 0,0,0);
    acc01 = __builtin_amdgcn_mfma_f32_16x16x32_bf16(a0, w1, acc01, 0,0,0);
    acc10 = __builtin_amdgcn_mfma_f32_16x16x32_bf16(a1, w0, acc10, 0,0,0);
    acc11 = __builtin_amdgcn_mfma_f32_16x16x32_bf16(a1, w1, acc11, 0,0,0);
  }

  float w20 = w2[n0 + lr];
  float w21 = w2[n0 + 16 + lr];
  #pragma unroll
  for (int bb=0; bb<2; ++bb){
    #pragma unroll
    for (int r=0;r<4;++r){
      float s0 = w20 - 2.f*(bb ? acc10[r] : acc00[r]);
      float s1 = w21 - 2.f*(bb ? acc11[r] : acc01[r]);
      float bv; int bi;
      if (s0 <= s1){ bv = s0; bi = n0 + lr; } else { bv = s1; bi = n0 + 16 + lr; }
      #pragma unroll
      for (int m=1; m<16; m<<=1){
        float ov = __shfl_xor(bv, m);
        int   oi = __shfl_xor(bi, m);
        if (ov < bv || (ov == bv && oi < bi)){ bv = ov; bi = oi; }
      }
      if (lr == 0){ int bl = bb*16 + lg*4 + r; sval[wv][bl] = bv; sidx[wv][bl] = bi; }
    }
  }
  __syncthreads();
  if (t < 32){
    float bv = sval[0][t]; int bi = sidx[0][t];
    #pragma unroll
    for (int w4=1; w4<4; ++w4){
      float ov = sval[w4][t]; int oi = sidx[w4][t];
      if (ov < bv || (ov == bv && oi < bi)){ bv = ov; bi = oi; }
    }
    u32 sb = __float_as_uint(bv);
    sb = (sb & 0x80000000u) ? ~sb : (sb | 0x80000000u);
    atomicMin(pack + b0 + t, ((u64)sb << 32) | (u32)bi);
  }
}

// K_update (r3 verbatim): h tile -> MFMA hX -> fused SOM update.
__global__ __launch_bounds__(512) void k_update(const void* X, const u16* XT, const void* W,
    const u64* pack, const int* passo, const int* total, void* out){
  __shared__ int sflag;
  __shared__ u16 hT[16][264];
  __shared__ float hpart[8][8];
  __shared__ float hs[16];
  int t = threadIdx.x;
  int isbf = sniff(X, t, &sflag);
  int wv = t>>6, l = t&63;
  int n0 = blockIdx.x * 16;

  float decay = expf(-(float)passo[0] / (float)total[0]);
  float taxa = 0.5f*decay, sigma = 32.f*decay;
  float inv2s2 = 1.f/(2.f*sigma*sigma);

  {
    int b = t & 255;
    int rbase = (t >> 8) * 8;
    int m = (int)(u32)(pack[b] & 0xffffffffu);
    int mx = m & 63, my = m >> 6;
    float hv[8];
    #pragma unroll
    for (int i=0;i<8;++i){
      int n = n0 + rbase + i;
      int dx = (n & 63) - mx;
      int dy = (n >> 6) - my;
      float h = expf(-(float)(dx*dx + dy*dy) * inv2s2);
      hv[i] = h;
      hT[rbase + i][b] = f2b(h);
    }
    #pragma unroll
    for (int i=0;i<8;++i){
      float s = hv[i];
      #pragma unroll
      for (int off=32; off; off>>=1) s += __shfl_down(s, off);
      if (l == 0) hpart[wv][i] = s;
    }
  }
  __syncthreads();
  if (t < 16){
    int g = (t >> 3) * 4;
    hs[t] = hpart[g][t&7] + hpart[g+1][t&7] + hpart[g+2][t&7] + hpart[g+3][t&7];
  }
  __syncthreads();

  int lr = l & 15, lg = l >> 4;
  int d0 = wv * 64;
  f32x4 acc[4];
  #pragma unroll
  for (int f=0;f<4;++f) acc[f] = (f32x4){0.f,0.f,0.f,0.f};

  #pragma unroll
  for (int ks=0; ks<8; ++ks){
    short8 a = *(const short8*)(&hT[lr][ks*32 + lg*8]);
    #pragma unroll
    for (int f=0; f<4; ++f){
      short8 bfr = *(const short8*)(XT + (size_t)(d0 + f*16 + lr)*BATCH + ks*32 + lg*8);
      acc[f] = __builtin_amdgcn_mfma_f32_16x16x32_bf16(a, bfr, acc[f], 0,0,0);
    }
  }

  float cc = taxa / (float)BATCH;
  #pragma unroll
  for (int r=0;r<4;++r){
    int n = n0 + lg*4 + r;
    float hsv = hs[lg*4 + r];
    #pragma unroll
    for (int f=0;f<4;++f){
      size_t gi = (size_t)n*DIM + d0 + f*16 + lr;
      float wv_ = ldv(W, gi, isbf);
      float o = wv_ + cc*(acc[f][r] - hsv*wv_);
      stv(out, gi, o, isbf);
    }
  }
}

extern "C" void kernel_launch(void* const* d_in, const int* in_sizes, int n_in,
                              void* d_out, int out_size, void* d_ws, size_t ws_size,
                              hipStream_t stream) {
  const void* X = d_in[0];      // (256, 512)
  const void* W = d_in[1];      // (4096, 512)
  // d_in[2] = localizacoes — recomputed on device as (n%64, n/64)
  const int* passo = (const int*)d_in[3];
  const int* total = (const int*)d_in[4];

  char* ws = (char*)d_ws;
  u64* pack = (u64*)(ws + 256);
  float* w2 = (float*)(ws + 2304);
  u16* XT   = (u16*)(ws + 18688);
  u16* Xb   = (u16*)(ws + 280832);
  u16* Wb   = (u16*)(ws + 542976);

  k_prep  <<<544, 256, 0, stream>>>(X, W, pack, w2, XT, Xb, Wb, passo, total, d_out);
  k_score <<<256, 256, 0, stream>>>(X, W, Xb, Wb, w2, pack);
  k_update<<<256, 512, 0, stream>>>(X, XT, W, pack, passo, total, d_out);
}